// Round 12
// baseline (106.925 us; speedup 1.0000x reference)
//
#include <hip/hip_runtime.h>

#define B_SZ   4096
#define H_SZ   200
#define D_SZ   128
#define N_SZ   256
#define ROWS   (B_SZ * H_SZ)      // 819200
#define BM     64
#define TPB    8                  // tiles per block
#define RPB    (BM * TPB)         // 512 rows per block
#define NBLK   (ROWS / RPB)       // 1600

typedef _Float16 f16;
typedef __attribute__((ext_vector_type(2))) _Float16 f16x2;
typedef __attribute__((ext_vector_type(8))) _Float16 f16x8;
typedef __attribute__((ext_vector_type(4))) float f32x4;

union H8 { f16x8 v; f16x2 p[4]; uint4 u; };

__device__ __forceinline__ f16x2 pkrtz(float a, float b) {
    return __builtin_bit_cast(f16x2, __builtin_amdgcn_cvt_pkrtz(a, b));
}

// Kernel 0a: embed_history f32 -> f16 (RTZ pack), 8 elems/thread
__global__ __launch_bounds__(256) void cvt_eh(const float* __restrict__ src,
                                              uint4* __restrict__ dst, int n8) {
    int i = blockIdx.x * 256 + threadIdx.x;
    if (i >= n8) return;
    const f32x4* p = (const f32x4*)src + (size_t)i * 2;
    f32x4 a = p[0], b = p[1];
    uint4 o;
    o.x = __builtin_bit_cast(unsigned, pkrtz(a[0], a[1]));
    o.y = __builtin_bit_cast(unsigned, pkrtz(a[2], a[3]));
    o.z = __builtin_bit_cast(unsigned, pkrtz(b[0], b[1]));
    o.w = __builtin_bit_cast(unsigned, pkrtz(b[2], b[3]));
    dst[i] = o;
}

// Kernel 0b: W1 [128][256] f32 -> W1T/16 [256][128] f16; tail blocks zero s1g/s2g
__global__ __launch_bounds__(256) void cvt_w1z(const float* __restrict__ src,
                                               f16* __restrict__ dst,
                                               float* __restrict__ s1g,
                                               float* __restrict__ s2g) {
    int i = blockIdx.x * 256 + threadIdx.x;
    if (i < N_SZ * D_SZ) {               // i = n*128 + d
        int n = i >> 7, d = i & 127;
        dst[i] = (f16)(src[d * N_SZ + n] * 0.0625f);
    }
    int z = i - N_SZ * D_SZ;
    if (z >= 0 && z < B_SZ) { s1g[z] = 0.f; s2g[z] = 0.f; }
}

// Main (r7 structure, VGPR<=64): 512 thr = 8 waves; wave w owns N-cols [32w,32w+32).
// Fused finish, DISTRIBUTED: all threads reduce apart; seg==0 lanes do exp +
// LDS atomics into block-local s1/s2; 4 global atomics per block at the end.
__global__ __launch_bounds__(512, 4) void nais_main(
    const int* __restrict__ history, const int* __restrict__ target,
    const uint4* __restrict__ ehh, const float* __restrict__ et,
    const f16* __restrict__ w1t, const float* __restrict__ b1,
    const float* __restrict__ w2,
    float* __restrict__ s1g, float* __restrict__ s2g)
{
    __shared__ uint4 AbufV[2][BM * 256 / 16];  // 32 KB swizzled [64][128] f16 x2
    __shared__ float apart[2][8][72];          // 4.6 KB (stride 72: 2-way banks)
    __shared__ f16   tgt_h[4][D_SZ];           // 1 KB (t * 16, f16)
    __shared__ int   tgt_i[4];
    __shared__ float dotd_lds[3][BM];          // triple-buffered (no barrier between
    __shared__ float m_lds[3][BM];             //  REDUCE(t-1) and construct(t+1))
    __shared__ float s1_loc[4], s2_loc[4];

    const int tid  = threadIdx.x;
    const int wid  = tid >> 6;
    const int lane = tid & 63;
    const int lo   = lane & 15;
    const int hi   = lane >> 4;
    const int row  = tid >> 3;
    const int seg  = tid & 7;
    const int blk  = blockIdx.x;
    const int b_base = (blk * RPB) / H_SZ;

    if (tid < 4) {
        int bb = b_base + tid;
        tgt_i[tid] = target[bb < B_SZ ? bb : (B_SZ - 1)];
        s1_loc[tid] = 0.f; s2_loc[tid] = 0.f;
    }
    __syncthreads();
    if (tid < 256) {   // preload 4 target rows as f16 * 16
        const int r4 = tid >> 6, j = (tid & 63) * 2;
        const float* src = et + (size_t)tgt_i[r4] * D_SZ + j;
        ((f16x2*)tgt_h)[tid] = pkrtz(src[0] * 16.f, src[1] * 16.f);
    }

    // W1T/16 fragments: wave wid owns cols [32*wid, 32*wid+32)
    f16x8 wfrag[4][2];
    #pragma unroll
    for (int ni = 0; ni < 2; ++ni) {
        int n = 32 * wid + 16 * ni + lo;
        #pragma unroll
        for (int ki = 0; ki < 4; ++ki)
            wfrag[ki][ni] = *(const f16x8*)(w1t + (size_t)n * D_SZ + 32 * ki + 8 * hi);
    }
    const int n0 = 32 * wid + 4 * hi;
    const f32x4 b1a = *(const f32x4*)(b1 + n0);
    const f32x4 b1b = *(const f32x4*)(b1 + n0 + 16);
    const f32x4 w2a = *(const f32x4*)(w2 + n0);
    const f32x4 w2b = *(const f32x4*)(w2 + n0 + 16);

    // gather pipeline prologue
    const int grow0 = blk * RPB + row;
    const int* hrow = history + grow0;
    int ih_cur = hrow[0];
    int ih_nxt = hrow[BM];
    uint4 hq0, hq1;
    {
        const uint4* p = ehh + (size_t)ih_cur * 16;
        hq0 = p[seg]; hq1 = p[8 + seg];
    }
    int b_loc = grow0 / H_SZ - b_base;                 // construct row's local b
    int rem   = grow0 - (b_loc + b_base) * H_SZ;
    int b_prev = b_loc;                                // lagged: local b at tile t-1
    __syncthreads();   // tgt_h ready

    // distributed reduce of tile TT (parity PAR): thread (row,seg) sums plane seg
    #define REDUCE(TT, PAR)                                                       \
    {                                                                             \
        float av = apart[PAR][seg][row];                                          \
        av += __shfl_xor(av, 1);                                                  \
        av += __shfl_xor(av, 2);                                                  \
        av += __shfl_xor(av, 4);                                                  \
        if (seg == 0) {                                                           \
            const int slot = (TT) % 3;                                            \
            float e   = m_lds[slot][row] * __expf(av);                            \
            float s2t = e * dotd_lds[slot][row];                                  \
            atomicAdd(&s1_loc[b_prev], e);                                        \
            atomicAdd(&s2_loc[b_prev], s2t);                                      \
        }                                                                         \
    }

    for (int t = 0; t < TPB; ++t) {
        char* Ab = (char*)AbufV[t & 1];

        // ---- construct tile t (f16 packed); dotd+mask -> LDS slot t%3 ----
        {
            H8 h1, h2, t1, t2, x1, x2;
            h1.u = hq0; h2.u = hq1;
            t1.v = *(const f16x8*)&tgt_h[b_loc][8 * seg];
            t2.v = *(const f16x8*)&tgt_h[b_loc][64 + 8 * seg];
            x1.v = h1.v * t1.v;        // 16*x, f16 packed
            x2.v = h2.v * t2.v;
            float s = 0.f;
            #pragma unroll
            for (int j = 0; j < 4; ++j) {
                s = __builtin_amdgcn_fdot2(h1.p[j], t1.p[j], s, false);
                s = __builtin_amdgcn_fdot2(h2.p[j], t2.p[j], s, false);
            }
            s += __shfl_xor(s, 1);
            s += __shfl_xor(s, 2);
            s += __shfl_xor(s, 4);
            if (seg == 0) {
                dotd_lds[t % 3][row] = s;   // raw 16x dotd; 0.0625 applied in sig
                m_lds[t % 3][row] = (ih_cur != tgt_i[b_loc]) ? 1.f : 0.f;
            }
            const unsigned sw = (unsigned)((row & 7) << 4);
            char* rb = Ab + row * 256;
            *(uint4*)(rb + (((unsigned)(16 * seg)) ^ sw))          = x1.u;
            *(uint4*)(rb + (128u + (((unsigned)(16 * seg)) ^ sw))) = x2.u;
        }
        __syncthreads();   // [single barrier per tile]

        // ---- prefetch next tile's gathers (hide under MFMA) ----
        if (t + 1 < TPB) {
            ih_cur = ih_nxt;
            if (t + 2 < TPB) ih_nxt = hrow[(t + 2) * BM];
            const uint4* p = ehh + (size_t)ih_cur * 16;
            hq0 = p[seg]; hq1 = p[8 + seg];
        }

        // ---- lagged distributed reduce of tile t-1 ----
        if (t > 0) REDUCE(t - 1, (t - 1) & 1)

        // ---- swapped MFMA + cheap epilogue ----
        #pragma unroll
        for (int mi = 0; mi < 4; ++mi) {
            const int rr = 16 * mi + lo;
            const unsigned swr = (unsigned)((rr & 7) << 4);
            f16x8 af[4];
            #pragma unroll
            for (int ki = 0; ki < 4; ++ki) {
                unsigned off = ((unsigned)(64 * ki + 16 * hi)) ^ swr;
                af[ki] = *(const f16x8*)(Ab + rr * 256 + off);
            }
            f32x4 acc0 = b1a;   // b1 folded into accumulator init
            f32x4 acc1 = b1b;
            __builtin_amdgcn_s_setprio(1);
            #pragma unroll
            for (int ki = 0; ki < 4; ++ki) {
                acc0 = __builtin_amdgcn_mfma_f32_16x16x32_f16(wfrag[ki][0], af[ki], acc0, 0, 0, 0);
                acc1 = __builtin_amdgcn_mfma_f32_16x16x32_f16(wfrag[ki][1], af[ki], acc1, 0, 0, 0);
            }
            __builtin_amdgcn_s_setprio(0);
            float v = fmaxf(acc0[0], 0.f) * w2a[0] + fmaxf(acc1[0], 0.f) * w2b[0];
            v += fmaxf(acc0[1], 0.f) * w2a[1] + fmaxf(acc1[1], 0.f) * w2b[1];
            v += fmaxf(acc0[2], 0.f) * w2a[2] + fmaxf(acc1[2], 0.f) * w2b[2];
            v += fmaxf(acc0[3], 0.f) * w2a[3] + fmaxf(acc1[3], 0.f) * w2b[3];
            v += __shfl_xor(v, 16);
            v += __shfl_xor(v, 32);
            if (lane < 16) apart[t & 1][wid][16 * mi + lane] = v;
        }

        // advance lagged b trackers (row += 64)
        b_prev = b_loc;
        rem += BM;
        if (rem >= H_SZ) { rem -= H_SZ; ++b_loc; }
    }
    __syncthreads();
    REDUCE(TPB - 1, (TPB - 1) & 1)
    #undef REDUCE
    __syncthreads();
    if (tid < 4 && b_base + tid < B_SZ) {
        atomicAdd(&s1g[b_base + tid], s1_loc[tid]);
        atomicAdd(&s2g[b_base + tid], s2_loc[tid]);
    }
}

// Epilogue: out[b] = sigmoid( (s2/16) / sqrt(s1) )
__global__ __launch_bounds__(256) void nais_sig(const float* __restrict__ s1g,
                                                const float* __restrict__ s2g,
                                                float* __restrict__ out) {
    int b = blockIdx.x * 256 + threadIdx.x;
    if (b >= B_SZ) return;
    float pred = 0.0625f * s2g[b] / sqrtf(s1g[b]);
    out[b] = 1.f / (1.f + __expf(-pred));
}

extern "C" void kernel_launch(void* const* d_in, const int* in_sizes, int n_in,
                              void* d_out, int out_size, void* d_ws, size_t ws_size,
                              hipStream_t stream) {
    const int*   history = (const int*)d_in[0];
    const int*   target  = (const int*)d_in[1];
    const float* eh      = (const float*)d_in[2];
    const float* et      = (const float*)d_in[3];
    const float* W1      = (const float*)d_in[4];
    const float* b1      = (const float*)d_in[5];
    const float* w2      = (const float*)d_in[6];
    float* out = (float*)d_out;

    char* ws = (char*)d_ws;
    uint4* ehh = (uint4*)ws;                                     // 25.6 MB (f16)
    f16*   w1t = (f16*)(ws + (size_t)100000 * D_SZ * 2);         // 64 KB
    float* s1g = (float*)(ws + (size_t)100000 * D_SZ * 2 + N_SZ * D_SZ * 2);
    float* s2g = s1g + B_SZ;                                     // 16 KB each

    const int n8 = 100000 * D_SZ / 8;
    cvt_eh<<<(n8 + 255) / 256, 256, 0, stream>>>(eh, ehh, n8);
    cvt_w1z<<<(N_SZ * D_SZ + B_SZ + 255) / 256, 256, 0, stream>>>(W1, w1t, s1g, s2g);
    nais_main<<<NBLK, 512, 0, stream>>>(history, target, ehh, et, w1t, b1, w2, s1g, s2g);
    nais_sig<<<(B_SZ + 255) / 256, 256, 0, stream>>>(s1g, s2g, out);
}

// Round 13
// 96.875 us; speedup vs baseline: 1.1038x; 1.1038x over previous
//
#include <hip/hip_runtime.h>

#define B_SZ   4096
#define H_SZ   200
#define D_SZ   128
#define N_SZ   256
#define ROWS   (B_SZ * H_SZ)      // 819200
#define BM     64
#define TPB    8                  // tiles per block
#define RPB    (BM * TPB)         // 512 rows per block
#define NBLK   (ROWS / RPB)       // 1600

typedef __attribute__((ext_vector_type(8))) short bf16x8;
typedef __attribute__((ext_vector_type(2))) float f32x2;
typedef __attribute__((ext_vector_type(4))) float f32x4;

__device__ __forceinline__ unsigned short f2bf(float f) {
    unsigned u = __builtin_bit_cast(unsigned, f);
    u += 0x7FFFu + ((u >> 16) & 1u);
    return (unsigned short)(u >> 16);
}
// pack two f32 to bf16x2 (truncate) in one v_perm_b32
__device__ __forceinline__ unsigned bfpack(f32x2 x) {
    return __builtin_amdgcn_perm(__builtin_bit_cast(unsigned, x[1]),
                                 __builtin_bit_cast(unsigned, x[0]), 0x07060302u);
}

// Kernel 0: W1 [128][256] f32 -> W1T [256][128] bf16 (RNE)
__global__ __launch_bounds__(256) void cvt_w1(const float* __restrict__ src,
                                              unsigned short* __restrict__ dst) {
    int i = blockIdx.x * 256 + threadIdx.x;   // i = n*128 + d
    int n = i >> 7, d = i & 127;
    dst[i] = f2bf(src[d * N_SZ + n]);
}

// Main (r7 structure): 512 thr = 8 waves; wave w owns N-cols [32w,32w+32).
// Direct f32 gather from embed_history (no pre-conversion pass):
// construct = v_pk_mul_f32 products + v_pk_add dotd (exact f32) + v_perm bf16 pack.
__global__ __launch_bounds__(512, 4) void nais_main(
    const int* __restrict__ history, const int* __restrict__ target,
    const float* __restrict__ eh, const float* __restrict__ et,
    const unsigned short* __restrict__ w1t, const float* __restrict__ b1,
    const float* __restrict__ w2,
    float* __restrict__ a_out, float* __restrict__ dotd_out)
{
    __shared__ uint4 AbufV[2][BM * 256 / 16];  // 32 KB swizzled [64][128] bf16 x2
    __shared__ float apart[2][8][BM];          // 4 KB
    __shared__ float tgt_f[4][D_SZ];           // 2 KB (f32)
    __shared__ int   tgt_i[4];

    const int tid  = threadIdx.x;
    const int wid  = tid >> 6;
    const int lane = tid & 63;
    const int lo   = lane & 15;
    const int hi   = lane >> 4;
    const int row  = tid >> 3;
    const int seg  = tid & 7;
    const int blk  = blockIdx.x;
    const int b_base = (blk * RPB) / H_SZ;

    if (tid < 4) {
        int bb = b_base + tid;
        tgt_i[tid] = target[bb < B_SZ ? bb : (B_SZ - 1)];
    }
    __syncthreads();
    {   // preload 4 target rows (f32): 512 threads cover 512 floats
        const int r4 = tid >> 7, d = tid & 127;
        tgt_f[r4][d] = et[(size_t)tgt_i[r4] * D_SZ + d];
    }

    // W1T bf16 fragments: wave wid owns cols [32*wid, 32*wid+32)
    bf16x8 wfrag[4][2];
    #pragma unroll
    for (int ni = 0; ni < 2; ++ni) {
        int n = 32 * wid + 16 * ni + lo;
        #pragma unroll
        for (int ki = 0; ki < 4; ++ki)
            wfrag[ki][ni] = *(const bf16x8*)(w1t + (size_t)n * D_SZ + 32 * ki + 8 * hi);
    }
    // b1 / w2 per-lane: n = 32wid + {0,16} + 4hi + r
    const int n0 = 32 * wid + 4 * hi;
    const f32x4 b1a = *(const f32x4*)(b1 + n0);
    const f32x4 b1b = *(const f32x4*)(b1 + n0 + 16);
    const f32x4 w2a = *(const f32x4*)(w2 + n0);
    const f32x4 w2b = *(const f32x4*)(w2 + n0 + 16);

    // gather pipeline prologue: thread covers k in [16seg, 16seg+16) (64 B of f32 row)
    const int grow0 = blk * RPB + row;
    const int* hrow = history + grow0;
    int ih_cur = hrow[0];
    int ih_nxt = hrow[BM];
    f32x4 hq0, hq1, hq2, hq3;
    {
        const f32x4* p = (const f32x4*)(eh + (size_t)ih_cur * D_SZ + 16 * seg);
        hq0 = p[0]; hq1 = p[1]; hq2 = p[2]; hq3 = p[3];
    }
    int b_loc = grow0 / H_SZ - b_base;
    int rem   = grow0 - (b_loc + b_base) * H_SZ;
    __syncthreads();   // tgt_f ready

    for (int t = 0; t < TPB; ++t) {
        char* Ab = (char*)AbufV[t & 1];
        const int gr = grow0 + t * BM;

        // ---- construct tile t: f32 packed mul + exact f32 dotd + bf16 trunc pack ----
        {
            const f32x2* tp = (const f32x2*)&tgt_f[b_loc][16 * seg];
            f32x2 h[8];
            h[0] = f32x2{hq0[0], hq0[1]}; h[1] = f32x2{hq0[2], hq0[3]};
            h[2] = f32x2{hq1[0], hq1[1]}; h[3] = f32x2{hq1[2], hq1[3]};
            h[4] = f32x2{hq2[0], hq2[1]}; h[5] = f32x2{hq2[2], hq2[3]};
            h[6] = f32x2{hq3[0], hq3[1]}; h[7] = f32x2{hq3[2], hq3[3]};
            f32x2 x[8];
            #pragma unroll
            for (int j = 0; j < 8; ++j) x[j] = h[j] * tp[j];
            f32x2 acc01 = x[0] + x[1], acc23 = x[2] + x[3];
            f32x2 acc45 = x[4] + x[5], acc67 = x[6] + x[7];
            f32x2 accA = acc01 + acc23, accB = acc45 + acc67;
            f32x2 accT = accA + accB;
            float s = accT[0] + accT[1];
            s += __shfl_xor(s, 1);
            s += __shfl_xor(s, 2);
            s += __shfl_xor(s, 4);
            if (seg == 0) dotd_out[gr] = s;
            uint4 o1 = uint4{bfpack(x[0]), bfpack(x[1]), bfpack(x[2]), bfpack(x[3])};
            uint4 o2 = uint4{bfpack(x[4]), bfpack(x[5]), bfpack(x[6]), bfpack(x[7])};
            const unsigned sw = (unsigned)((row & 7) << 4);
            char* rb = Ab + row * 256;
            *(uint4*)(rb + (((unsigned)(32 * seg)) ^ sw))      = o1;
            *(uint4*)(rb + (((unsigned)(32 * seg + 16)) ^ sw)) = o2;
        }
        __syncthreads();   // [single barrier per tile]

        // ---- prefetch next tile's gathers (hide under MFMA) ----
        if (t + 1 < TPB) {
            ih_cur = ih_nxt;
            if (t + 2 < TPB) ih_nxt = hrow[(t + 2) * BM];
            const f32x4* p = (const f32x4*)(eh + (size_t)ih_cur * D_SZ + 16 * seg);
            hq0 = p[0]; hq1 = p[1]; hq2 = p[2]; hq3 = p[3];
        }

        // ---- lagged reduction of tile t-1's apart ----
        if (t > 0 && tid < BM) {
            const float* ap = &apart[(t - 1) & 1][0][tid];
            float a = ap[0];
            #pragma unroll
            for (int w = 1; w < 8; ++w) a += ap[w * BM];
            a_out[blk * RPB + (t - 1) * BM + tid] = a;
        }

        // ---- swapped MFMA (bf16) + cheap epilogue ----
        #pragma unroll
        for (int mi = 0; mi < 4; ++mi) {
            const int rr = 16 * mi + lo;
            const unsigned swr = (unsigned)((rr & 7) << 4);
            bf16x8 af[4];
            #pragma unroll
            for (int ki = 0; ki < 4; ++ki) {
                unsigned off = ((unsigned)(64 * ki + 16 * hi)) ^ swr;
                af[ki] = *(const bf16x8*)(Ab + rr * 256 + off);
            }
            f32x4 acc0 = b1a;   // b1 folded into accumulator init
            f32x4 acc1 = b1b;
            __builtin_amdgcn_s_setprio(1);
            #pragma unroll
            for (int ki = 0; ki < 4; ++ki) {
                acc0 = __builtin_amdgcn_mfma_f32_16x16x32_bf16(wfrag[ki][0], af[ki], acc0, 0, 0, 0);
                acc1 = __builtin_amdgcn_mfma_f32_16x16x32_bf16(wfrag[ki][1], af[ki], acc1, 0, 0, 0);
            }
            __builtin_amdgcn_s_setprio(0);
            float v = fmaxf(acc0[0], 0.f) * w2a[0] + fmaxf(acc1[0], 0.f) * w2b[0];
            v += fmaxf(acc0[1], 0.f) * w2a[1] + fmaxf(acc1[1], 0.f) * w2b[1];
            v += fmaxf(acc0[2], 0.f) * w2a[2] + fmaxf(acc1[2], 0.f) * w2b[2];
            v += fmaxf(acc0[3], 0.f) * w2a[3] + fmaxf(acc1[3], 0.f) * w2b[3];
            v += __shfl_xor(v, 16);
            v += __shfl_xor(v, 32);
            if (lane < 16) apart[t & 1][wid][16 * mi + lane] = v;
        }

        // advance incremental b_loc (row += 64)
        rem += BM;
        if (rem >= H_SZ) { rem -= H_SZ; ++b_loc; }
    }
    __syncthreads();
    if (tid < BM) {   // final tile's reduction
        const float* ap = &apart[(TPB - 1) & 1][0][tid];
        float a = ap[0];
        #pragma unroll
        for (int w = 1; w < 8; ++w) a += ap[w * BM];
        a_out[blk * RPB + (TPB - 1) * BM + tid] = a;
    }
}

// Finish: per-b masked exp, beta=0.5 power norm, weighted dot, sigmoid
__global__ __launch_bounds__(64) void nais_finish(
    const int* __restrict__ history, const int* __restrict__ target,
    const float* __restrict__ a_in, const float* __restrict__ dotd_in,
    float* __restrict__ out)
{
    const int b    = blockIdx.x;
    const int lane = threadIdx.x;
    const int tgt  = target[b];
    float s1 = 0.f, s2 = 0.f;
    for (int h = lane; h < H_SZ; h += 64) {
        int rg = b * H_SZ + h;
        float e = (history[rg] != tgt) ? __expf(a_in[rg]) : 0.f;
        s1 += e;
        s2 += e * dotd_in[rg];
    }
    #pragma unroll
    for (int o = 1; o < 64; o <<= 1) {
        s1 += __shfl_xor(s1, o);
        s2 += __shfl_xor(s2, o);
    }
    if (lane == 0) {
        float pred = s2 / sqrtf(s1);
        out[b] = 1.f / (1.f + __expf(-pred));
    }
}

extern "C" void kernel_launch(void* const* d_in, const int* in_sizes, int n_in,
                              void* d_out, int out_size, void* d_ws, size_t ws_size,
                              hipStream_t stream) {
    const int*   history = (const int*)d_in[0];
    const int*   target  = (const int*)d_in[1];
    const float* eh      = (const float*)d_in[2];
    const float* et      = (const float*)d_in[3];
    const float* W1      = (const float*)d_in[4];
    const float* b1      = (const float*)d_in[5];
    const float* w2      = (const float*)d_in[6];
    float* out = (float*)d_out;

    char* ws = (char*)d_ws;
    unsigned short* w1t = (unsigned short*)ws;        // 64 KB bf16
    float* a_ws    = (float*)(ws + N_SZ * D_SZ * 2);
    float* dotd_ws = a_ws + ROWS;                     // 3.3 MB each

    cvt_w1<<<(N_SZ * D_SZ) / 256, 256, 0, stream>>>(W1, w1t);
    nais_main<<<NBLK, 512, 0, stream>>>(history, target, eh, et, w1t, b1, w2, a_ws, dotd_ws);
    nais_finish<<<B_SZ, 64, 0, stream>>>(history, target, a_ws, dotd_ws, out);
}

// Round 14
// 94.087 us; speedup vs baseline: 1.1365x; 1.0296x over previous
//
#include <hip/hip_runtime.h>

#define B_SZ   4096
#define H_SZ   200
#define D_SZ   128
#define N_SZ   256
#define ROWS   (B_SZ * H_SZ)      // 819200
#define BM     64
#define TPB    4                  // tiles per block (short blocks: smaller tail)
#define RPB    (BM * TPB)         // 256 rows per block
#define NBLK   (ROWS / RPB)       // 3200

typedef __attribute__((ext_vector_type(8))) short bf16x8;
typedef __attribute__((ext_vector_type(4))) float f32x4;

__device__ __forceinline__ unsigned short f2bf(float f) {
    unsigned u = __builtin_bit_cast(unsigned, f);
    u += 0x7FFFu + ((u >> 16) & 1u);
    return (unsigned short)(u >> 16);
}
// pack two f32 to bf16x2 (truncate) in one v_perm_b32
__device__ __forceinline__ unsigned bfpack2(float a, float b) {
    return __builtin_amdgcn_perm(__builtin_bit_cast(unsigned, b),
                                 __builtin_bit_cast(unsigned, a), 0x07060302u);
}

// Kernel 0: W1 [128][256] f32 -> W1T [256][128] bf16 (RNE)
__global__ __launch_bounds__(256) void cvt_w1(const float* __restrict__ src,
                                              unsigned short* __restrict__ dst) {
    int i = blockIdx.x * 256 + threadIdx.x;   // i = n*128 + d
    int n = i >> 7, d = i & 127;
    dst[i] = f2bf(src[d * N_SZ + n]);
}

// Main (r7 structure): 512 thr = 8 waves; wave w owns N-cols [32w,32w+32).
// f32 gather as two 32B chunks (d in [8s,8s+8) u [64+8s,64+8s+8)) so LDS writes
// use the conflict-clean {16s, 128+16s} split-chunk pattern.
__global__ __launch_bounds__(512, 4) void nais_main(
    const int* __restrict__ history, const int* __restrict__ target,
    const float* __restrict__ eh, const float* __restrict__ et,
    const unsigned short* __restrict__ w1t, const float* __restrict__ b1,
    const float* __restrict__ w2,
    float* __restrict__ a_out, float* __restrict__ dotd_out)
{
    __shared__ uint4 AbufV[2][BM * 256 / 16];  // 32 KB swizzled [64][128] bf16 x2
    __shared__ float apart[2][8][BM];          // 4 KB
    __shared__ float tgt_f[4][D_SZ];           // 2 KB (f32)
    __shared__ int   tgt_i[4];

    const int tid  = threadIdx.x;
    const int wid  = tid >> 6;
    const int lane = tid & 63;
    const int lo   = lane & 15;
    const int hi   = lane >> 4;
    const int row  = tid >> 3;
    const int seg  = tid & 7;
    const int blk  = blockIdx.x;
    const int b_base = (blk * RPB) / H_SZ;

    if (tid < 4) {
        int bb = b_base + tid;
        tgt_i[tid] = target[bb < B_SZ ? bb : (B_SZ - 1)];
    }
    __syncthreads();
    {   // preload 4 target rows (f32): 512 threads cover 512 floats
        const int r4 = tid >> 7, d = tid & 127;
        tgt_f[r4][d] = et[(size_t)tgt_i[r4] * D_SZ + d];
    }

    // W1T bf16 fragments: wave wid owns cols [32*wid, 32*wid+32)
    bf16x8 wfrag[4][2];
    #pragma unroll
    for (int ni = 0; ni < 2; ++ni) {
        int n = 32 * wid + 16 * ni + lo;
        #pragma unroll
        for (int ki = 0; ki < 4; ++ki)
            wfrag[ki][ni] = *(const bf16x8*)(w1t + (size_t)n * D_SZ + 32 * ki + 8 * hi);
    }
    // b1 / w2 per-lane: n = 32wid + {0,16} + 4hi + r
    const int n0 = 32 * wid + 4 * hi;
    const f32x4 b1a = *(const f32x4*)(b1 + n0);
    const f32x4 b1b = *(const f32x4*)(b1 + n0 + 16);
    const f32x4 w2a = *(const f32x4*)(w2 + n0);
    const f32x4 w2b = *(const f32x4*)(w2 + n0 + 16);

    // gather prologue: two 32B chunks per row: d in [8s,8s+8) and [64+8s,64+8s+8)
    const int grow0 = blk * RPB + row;
    const int* hrow = history + grow0;
    int ih_cur = hrow[0];
    int ih_nxt = hrow[BM];
    f32x4 hq0, hq1, hq2, hq3;
    {
        const float* base = eh + (size_t)ih_cur * D_SZ + 8 * seg;
        hq0 = *(const f32x4*)(base);      hq1 = *(const f32x4*)(base + 4);
        hq2 = *(const f32x4*)(base + 64); hq3 = *(const f32x4*)(base + 68);
    }
    int b_loc = grow0 / H_SZ - b_base;
    int rem   = grow0 - (b_loc + b_base) * H_SZ;
    __syncthreads();   // tgt_f ready

    for (int t = 0; t < TPB; ++t) {
        char* Ab = (char*)AbufV[t & 1];
        const int gr = grow0 + t * BM;

        // ---- construct tile t: pk f32 mul + exact f32 dotd + bf16 trunc pack ----
        {
            const float* tp = &tgt_f[b_loc][8 * seg];
            f32x4 t0 = *(const f32x4*)(tp);      f32x4 t1 = *(const f32x4*)(tp + 4);
            f32x4 t2 = *(const f32x4*)(tp + 64); f32x4 t3 = *(const f32x4*)(tp + 68);
            f32x4 x0 = hq0 * t0, x1 = hq1 * t1, x2 = hq2 * t2, x3 = hq3 * t3;
            f32x4 sx = (x0 + x1) + (x2 + x3);
            float s = (sx[0] + sx[1]) + (sx[2] + sx[3]);
            s += __shfl_xor(s, 1);
            s += __shfl_xor(s, 2);
            s += __shfl_xor(s, 4);
            if (seg == 0) dotd_out[gr] = s;
            uint4 o1 = uint4{bfpack2(x0[0], x0[1]), bfpack2(x0[2], x0[3]),
                             bfpack2(x1[0], x1[1]), bfpack2(x1[2], x1[3])};
            uint4 o2 = uint4{bfpack2(x2[0], x2[1]), bfpack2(x2[2], x2[3]),
                             bfpack2(x3[0], x3[1]), bfpack2(x3[2], x3[3])};
            const unsigned sw = (unsigned)((row & 7) << 4);
            char* rb = Ab + row * 256;
            *(uint4*)(rb + (((unsigned)(16 * seg)) ^ sw))          = o1;
            *(uint4*)(rb + (128u + (((unsigned)(16 * seg)) ^ sw))) = o2;
        }
        __syncthreads();   // [single barrier per tile]

        // ---- prefetch next tile's gathers (hide under MFMA) ----
        if (t + 1 < TPB) {
            ih_cur = ih_nxt;
            if (t + 2 < TPB) ih_nxt = hrow[(t + 2) * BM];
            const float* base = eh + (size_t)ih_cur * D_SZ + 8 * seg;
            hq0 = *(const f32x4*)(base);      hq1 = *(const f32x4*)(base + 4);
            hq2 = *(const f32x4*)(base + 64); hq3 = *(const f32x4*)(base + 68);
        }

        // ---- lagged reduction of tile t-1's apart ----
        if (t > 0 && tid < BM) {
            const float* ap = &apart[(t - 1) & 1][0][tid];
            float a = ap[0];
            #pragma unroll
            for (int w = 1; w < 8; ++w) a += ap[w * BM];
            a_out[blk * RPB + (t - 1) * BM + tid] = a;
        }

        // ---- swapped MFMA (bf16) + cheap epilogue ----
        #pragma unroll
        for (int mi = 0; mi < 4; ++mi) {
            const int rr = 16 * mi + lo;
            const unsigned swr = (unsigned)((rr & 7) << 4);
            bf16x8 af[4];
            #pragma unroll
            for (int ki = 0; ki < 4; ++ki) {
                unsigned off = ((unsigned)(64 * ki + 16 * hi)) ^ swr;
                af[ki] = *(const bf16x8*)(Ab + rr * 256 + off);
            }
            f32x4 acc0 = b1a;   // b1 folded into accumulator init
            f32x4 acc1 = b1b;
            __builtin_amdgcn_s_setprio(1);
            #pragma unroll
            for (int ki = 0; ki < 4; ++ki) {
                acc0 = __builtin_amdgcn_mfma_f32_16x16x32_bf16(wfrag[ki][0], af[ki], acc0, 0, 0, 0);
                acc1 = __builtin_amdgcn_mfma_f32_16x16x32_bf16(wfrag[ki][1], af[ki], acc1, 0, 0, 0);
            }
            __builtin_amdgcn_s_setprio(0);
            float v = fmaxf(acc0[0], 0.f) * w2a[0] + fmaxf(acc1[0], 0.f) * w2b[0];
            v += fmaxf(acc0[1], 0.f) * w2a[1] + fmaxf(acc1[1], 0.f) * w2b[1];
            v += fmaxf(acc0[2], 0.f) * w2a[2] + fmaxf(acc1[2], 0.f) * w2b[2];
            v += fmaxf(acc0[3], 0.f) * w2a[3] + fmaxf(acc1[3], 0.f) * w2b[3];
            v += __shfl_xor(v, 16);
            v += __shfl_xor(v, 32);
            if (lane < 16) apart[t & 1][wid][16 * mi + lane] = v;
        }

        // advance incremental b_loc (row += 64)
        rem += BM;
        if (rem >= H_SZ) { rem -= H_SZ; ++b_loc; }
    }
    __syncthreads();
    if (tid < BM) {   // final tile's reduction
        const float* ap = &apart[(TPB - 1) & 1][0][tid];
        float a = ap[0];
        #pragma unroll
        for (int w = 1; w < 8; ++w) a += ap[w * BM];
        a_out[blk * RPB + (TPB - 1) * BM + tid] = a;
    }
}

// Finish: per-b masked exp, beta=0.5 power norm, weighted dot, sigmoid
__global__ __launch_bounds__(64) void nais_finish(
    const int* __restrict__ history, const int* __restrict__ target,
    const float* __restrict__ a_in, const float* __restrict__ dotd_in,
    float* __restrict__ out)
{
    const int b    = blockIdx.x;
    const int lane = threadIdx.x;
    const int tgt  = target[b];
    float s1 = 0.f, s2 = 0.f;
    for (int h = lane; h < H_SZ; h += 64) {
        int rg = b * H_SZ + h;
        float e = (history[rg] != tgt) ? __expf(a_in[rg]) : 0.f;
        s1 += e;
        s2 += e * dotd_in[rg];
    }
    #pragma unroll
    for (int o = 1; o < 64; o <<= 1) {
        s1 += __shfl_xor(s1, o);
        s2 += __shfl_xor(s2, o);
    }
    if (lane == 0) {
        float pred = s2 / sqrtf(s1);
        out[b] = 1.f / (1.f + __expf(-pred));
    }
}

extern "C" void kernel_launch(void* const* d_in, const int* in_sizes, int n_in,
                              void* d_out, int out_size, void* d_ws, size_t ws_size,
                              hipStream_t stream) {
    const int*   history = (const int*)d_in[0];
    const int*   target  = (const int*)d_in[1];
    const float* eh      = (const float*)d_in[2];
    const float* et      = (const float*)d_in[3];
    const float* W1      = (const float*)d_in[4];
    const float* b1      = (const float*)d_in[5];
    const float* w2      = (const float*)d_in[6];
    float* out = (float*)d_out;

    char* ws = (char*)d_ws;
    unsigned short* w1t = (unsigned short*)ws;        // 64 KB bf16
    float* a_ws    = (float*)(ws + N_SZ * D_SZ * 2);
    float* dotd_ws = a_ws + ROWS;                     // 3.3 MB each

    cvt_w1<<<(N_SZ * D_SZ) / 256, 256, 0, stream>>>(W1, w1t);
    nais_main<<<NBLK, 512, 0, stream>>>(history, target, eh, et, w1t, b1, w2, a_ws, dotd_ws);
    nais_finish<<<B_SZ, 64, 0, stream>>>(history, target, a_ws, dotd_ws, out);
}

// Round 15
// 93.601 us; speedup vs baseline: 1.1424x; 1.0052x over previous
//
#include <hip/hip_runtime.h>

#define B_SZ   4096
#define H_SZ   200
#define D_SZ   128
#define N_SZ   256
#define ROWS   (B_SZ * H_SZ)      // 819200
#define BM     64
#define TPB    8                  // tiles per block
#define RPB    (BM * TPB)         // 512 rows per block
#define NBLK   (ROWS / RPB)       // 1600

typedef __attribute__((ext_vector_type(8))) short bf16x8;
typedef __attribute__((ext_vector_type(4))) float f32x4;

__device__ __forceinline__ unsigned short f2bf(float f) {
    unsigned u = __builtin_bit_cast(unsigned, f);
    u += 0x7FFFu + ((u >> 16) & 1u);
    return (unsigned short)(u >> 16);
}
// pack two f32 to bf16x2 (truncate) in one v_perm_b32
__device__ __forceinline__ unsigned bfpack2(float a, float b) {
    return __builtin_amdgcn_perm(__builtin_bit_cast(unsigned, b),
                                 __builtin_bit_cast(unsigned, a), 0x07060302u);
}

// Kernel 0: W1 [128][256] f32 -> W1T [256][128] bf16 (RNE)
__global__ __launch_bounds__(256) void cvt_w1(const float* __restrict__ src,
                                              unsigned short* __restrict__ dst) {
    int i = blockIdx.x * 256 + threadIdx.x;   // i = n*128 + d
    int n = i >> 7, d = i & 127;
    dst[i] = f2bf(src[d * N_SZ + n]);
}

// Main (r7 structure): 512 thr = 8 waves; wave w owns N-cols [32w,32w+32).
// TPB=8 (amortized prologue) + clean split-chunk LDS writes + trimmed prologue.
__global__ __launch_bounds__(512, 4) void nais_main(
    const int* __restrict__ history, const int* __restrict__ target,
    const float* __restrict__ eh, const float* __restrict__ et,
    const unsigned short* __restrict__ w1t, const float* __restrict__ b1,
    const float* __restrict__ w2,
    float* __restrict__ a_out, float* __restrict__ dotd_out)
{
    __shared__ uint4 AbufV[2][BM * 256 / 16];  // 32 KB swizzled [64][128] bf16 x2
    __shared__ float apart[2][8][BM];          // 4 KB
    __shared__ float tgt_f[4][D_SZ];           // 2 KB (f32)

    const int tid  = threadIdx.x;
    const int wid  = tid >> 6;
    const int lane = tid & 63;
    const int lo   = lane & 15;
    const int hi   = lane >> 4;
    const int row  = tid >> 3;
    const int seg  = tid & 7;
    const int blk  = blockIdx.x;
    const int b_base = (blk * RPB) / H_SZ;

    {   // preload 4 target rows (f32), no tgt_i staging: direct broadcast reads
        const int r4 = tid >> 7, d = tid & 127;
        int bb = b_base + r4;
        int tg = target[bb < B_SZ ? bb : (B_SZ - 1)];
        tgt_f[r4][d] = et[(size_t)tg * D_SZ + d];
    }

    // W1T bf16 fragments: wave wid owns cols [32*wid, 32*wid+32)
    bf16x8 wfrag[4][2];
    #pragma unroll
    for (int ni = 0; ni < 2; ++ni) {
        int n = 32 * wid + 16 * ni + lo;
        #pragma unroll
        for (int ki = 0; ki < 4; ++ki)
            wfrag[ki][ni] = *(const bf16x8*)(w1t + (size_t)n * D_SZ + 32 * ki + 8 * hi);
    }
    // b1 / w2 per-lane: n = 32wid + {0,16} + 4hi + r
    const int n0 = 32 * wid + 4 * hi;
    const f32x4 b1a = *(const f32x4*)(b1 + n0);
    const f32x4 b1b = *(const f32x4*)(b1 + n0 + 16);
    const f32x4 w2a = *(const f32x4*)(w2 + n0);
    const f32x4 w2b = *(const f32x4*)(w2 + n0 + 16);

    // gather prologue: two 32B chunks per row: d in [8s,8s+8) and [64+8s,64+8s+8)
    const int grow0 = blk * RPB + row;
    const int* hrow = history + grow0;
    int ih_cur = hrow[0];
    int ih_nxt = hrow[BM];
    f32x4 hq0, hq1, hq2, hq3;
    {
        const float* base = eh + (size_t)ih_cur * D_SZ + 8 * seg;
        hq0 = *(const f32x4*)(base);      hq1 = *(const f32x4*)(base + 4);
        hq2 = *(const f32x4*)(base + 64); hq3 = *(const f32x4*)(base + 68);
    }
    int b_loc = grow0 / H_SZ - b_base;
    int rem   = grow0 - (b_loc + b_base) * H_SZ;
    __syncthreads();   // tgt_f ready

    for (int t = 0; t < TPB; ++t) {
        char* Ab = (char*)AbufV[t & 1];
        const int gr = grow0 + t * BM;

        // ---- construct tile t: pk f32 mul + exact f32 dotd + bf16 trunc pack ----
        {
            const float* tp = &tgt_f[b_loc][8 * seg];
            f32x4 t0 = *(const f32x4*)(tp);      f32x4 t1 = *(const f32x4*)(tp + 4);
            f32x4 t2 = *(const f32x4*)(tp + 64); f32x4 t3 = *(const f32x4*)(tp + 68);
            f32x4 x0 = hq0 * t0, x1 = hq1 * t1, x2 = hq2 * t2, x3 = hq3 * t3;
            f32x4 sx = (x0 + x1) + (x2 + x3);
            float s = (sx[0] + sx[1]) + (sx[2] + sx[3]);
            s += __shfl_xor(s, 1);
            s += __shfl_xor(s, 2);
            s += __shfl_xor(s, 4);
            if (seg == 0) dotd_out[gr] = s;
            uint4 o1 = uint4{bfpack2(x0[0], x0[1]), bfpack2(x0[2], x0[3]),
                             bfpack2(x1[0], x1[1]), bfpack2(x1[2], x1[3])};
            uint4 o2 = uint4{bfpack2(x2[0], x2[1]), bfpack2(x2[2], x2[3]),
                             bfpack2(x3[0], x3[1]), bfpack2(x3[2], x3[3])};
            const unsigned sw = (unsigned)((row & 7) << 4);
            char* rb = Ab + row * 256;
            *(uint4*)(rb + (((unsigned)(16 * seg)) ^ sw))          = o1;
            *(uint4*)(rb + (128u + (((unsigned)(16 * seg)) ^ sw))) = o2;
        }
        __syncthreads();   // [single barrier per tile]

        // ---- prefetch next tile's gathers (hide under MFMA) ----
        if (t + 1 < TPB) {
            ih_cur = ih_nxt;
            if (t + 2 < TPB) ih_nxt = hrow[(t + 2) * BM];
            const float* base = eh + (size_t)ih_cur * D_SZ + 8 * seg;
            hq0 = *(const f32x4*)(base);      hq1 = *(const f32x4*)(base + 4);
            hq2 = *(const f32x4*)(base + 64); hq3 = *(const f32x4*)(base + 68);
        }

        // ---- lagged reduction of tile t-1's apart ----
        if (t > 0 && tid < BM) {
            const float* ap = &apart[(t - 1) & 1][0][tid];
            float a = ap[0];
            #pragma unroll
            for (int w = 1; w < 8; ++w) a += ap[w * BM];
            a_out[blk * RPB + (t - 1) * BM + tid] = a;
        }

        // ---- swapped MFMA (bf16) + cheap epilogue ----
        #pragma unroll
        for (int mi = 0; mi < 4; ++mi) {
            const int rr = 16 * mi + lo;
            const unsigned swr = (unsigned)((rr & 7) << 4);
            bf16x8 af[4];
            #pragma unroll
            for (int ki = 0; ki < 4; ++ki) {
                unsigned off = ((unsigned)(64 * ki + 16 * hi)) ^ swr;
                af[ki] = *(const bf16x8*)(Ab + rr * 256 + off);
            }
            f32x4 acc0 = b1a;   // b1 folded into accumulator init
            f32x4 acc1 = b1b;
            __builtin_amdgcn_s_setprio(1);
            #pragma unroll
            for (int ki = 0; ki < 4; ++ki) {
                acc0 = __builtin_amdgcn_mfma_f32_16x16x32_bf16(wfrag[ki][0], af[ki], acc0, 0, 0, 0);
                acc1 = __builtin_amdgcn_mfma_f32_16x16x32_bf16(wfrag[ki][1], af[ki], acc1, 0, 0, 0);
            }
            __builtin_amdgcn_s_setprio(0);
            float v = fmaxf(acc0[0], 0.f) * w2a[0] + fmaxf(acc1[0], 0.f) * w2b[0];
            v += fmaxf(acc0[1], 0.f) * w2a[1] + fmaxf(acc1[1], 0.f) * w2b[1];
            v += fmaxf(acc0[2], 0.f) * w2a[2] + fmaxf(acc1[2], 0.f) * w2b[2];
            v += fmaxf(acc0[3], 0.f) * w2a[3] + fmaxf(acc1[3], 0.f) * w2b[3];
            v += __shfl_xor(v, 16);
            v += __shfl_xor(v, 32);
            if (lane < 16) apart[t & 1][wid][16 * mi + lane] = v;
        }

        // advance incremental b_loc (row += 64)
        rem += BM;
        if (rem >= H_SZ) { rem -= H_SZ; ++b_loc; }
    }
    __syncthreads();
    if (tid < BM) {   // final tile's reduction
        const float* ap = &apart[(TPB - 1) & 1][0][tid];
        float a = ap[0];
        #pragma unroll
        for (int w = 1; w < 8; ++w) a += ap[w * BM];
        a_out[blk * RPB + (TPB - 1) * BM + tid] = a;
    }
}

// Finish: per-b masked exp, beta=0.5 power norm, weighted dot, sigmoid
__global__ __launch_bounds__(64) void nais_finish(
    const int* __restrict__ history, const int* __restrict__ target,
    const float* __restrict__ a_in, const float* __restrict__ dotd_in,
    float* __restrict__ out)
{
    const int b    = blockIdx.x;
    const int lane = threadIdx.x;
    const int tgt  = target[b];
    float s1 = 0.f, s2 = 0.f;
    for (int h = lane; h < H_SZ; h += 64) {
        int rg = b * H_SZ + h;
        float e = (history[rg] != tgt) ? __expf(a_in[rg]) : 0.f;
        s1 += e;
        s2 += e * dotd_in[rg];
    }
    #pragma unroll
    for (int o = 1; o < 64; o <<= 1) {
        s1 += __shfl_xor(s1, o);
        s2 += __shfl_xor(s2, o);
    }
    if (lane == 0) {
        float pred = s2 / sqrtf(s1);
        out[b] = 1.f / (1.f + __expf(-pred));
    }
}

extern "C" void kernel_launch(void* const* d_in, const int* in_sizes, int n_in,
                              void* d_out, int out_size, void* d_ws, size_t ws_size,
                              hipStream_t stream) {
    const int*   history = (const int*)d_in[0];
    const int*   target  = (const int*)d_in[1];
    const float* eh      = (const float*)d_in[2];
    const float* et      = (const float*)d_in[3];
    const float* W1      = (const float*)d_in[4];
    const float* b1      = (const float*)d_in[5];
    const float* w2      = (const float*)d_in[6];
    float* out = (float*)d_out;

    char* ws = (char*)d_ws;
    unsigned short* w1t = (unsigned short*)ws;        // 64 KB bf16
    float* a_ws    = (float*)(ws + N_SZ * D_SZ * 2);
    float* dotd_ws = a_ws + ROWS;                     // 3.3 MB each

    cvt_w1<<<(N_SZ * D_SZ) / 256, 256, 0, stream>>>(W1, w1t);
    nais_main<<<NBLK, 512, 0, stream>>>(history, target, eh, et, w1t, b1, w2, a_ws, dotd_ws);
    nais_finish<<<B_SZ, 64, 0, stream>>>(history, target, a_ws, dotd_ws, out);
}